// Round 1
// baseline (375.068 us; speedup 1.0000x reference)
//
#include <hip/hip_runtime.h>

// Problem constants
#define B_ 8
#define S_ 4096
#define E_ 512
#define H_ 8
#define D_ 64
#define M_TOT 32768   // B*S

typedef __attribute__((ext_vector_type(8))) short short8;
typedef __attribute__((ext_vector_type(4))) float f32x4;
typedef __attribute__((ext_vector_type(4))) unsigned int u32x4;

__device__ __forceinline__ float bf2f(unsigned short u) {
  union { unsigned int i; float f; } v; v.i = ((unsigned int)u) << 16; return v.f;
}
__device__ __forceinline__ unsigned short f2bf(float f) {
  union { float f; unsigned int i; } v; v.f = f;
  unsigned int r = v.i + 0x7FFFu + ((v.i >> 16) & 1u);
  return (unsigned short)(r >> 16);
}

// ---------------------------------------------------------------------------
// Cast x (f32 -> bf16), 4 elems/thread
__global__ __launch_bounds__(256) void cast_x_kernel(
    const float* __restrict__ x, unsigned short* __restrict__ xb) {
  int i = (blockIdx.x * 256 + threadIdx.x) * 4;
  float4 v = *(const float4*)(x + i);
  ushort4 o;
  o.x = f2bf(v.x); o.y = f2bf(v.y); o.z = f2bf(v.z); o.w = f2bf(v.w);
  *(ushort4*)(xb + i) = o;
}

// Cast weights: Wq/Wk/Wv -> Wcat[1536][512] bf16, Wo -> bf16, biases -> bcat
__global__ __launch_bounds__(256) void cast_w_kernel(
    const float* __restrict__ Wq, const float* __restrict__ Wk,
    const float* __restrict__ Wv, const float* __restrict__ Wo,
    const float* __restrict__ bq, const float* __restrict__ bk,
    const float* __restrict__ bv,
    unsigned short* __restrict__ Wcat, unsigned short* __restrict__ Wob,
    float* __restrict__ bcat) {
  int i = blockIdx.x * 256 + threadIdx.x;  // 0..262143
  Wcat[i]          = f2bf(Wq[i]);
  Wcat[262144 + i] = f2bf(Wk[i]);
  Wcat[524288 + i] = f2bf(Wv[i]);
  Wob[i]           = f2bf(Wo[i]);
  if (i < 512) { bcat[i] = bq[i]; bcat[512 + i] = bk[i]; bcat[1024 + i] = bv[i]; }
}

// ---------------------------------------------------------------------------
// C[m][n] = sum_k A[m][k] * Bw[n][k] + bias[n]     (both operands row-major, K=512)
// BM=BN=128, BK=64, 4 waves (2x2), each wave 64x64 via 4x4 x mfma_16x16x32_bf16.
// LDS tiles XOR-swizzled in 16B chunks: chunk_slot = c ^ (row&7)  (conflict-free-ish).
template<int OUT_BF16>
__global__ __launch_bounds__(256, 2) void gemm_bt(
    const unsigned short* __restrict__ A,   // [M][512] bf16
    const unsigned short* __restrict__ Bw,  // [N][512] bf16
    const float* __restrict__ bias,         // [N] f32
    void* __restrict__ Cv,                  // [M][N] f32 or bf16
    int N, int ntiles) {
  __shared__ u32x4 As[1024];  // 128 rows x 8 chunks of 16B
  __shared__ u32x4 Bs[1024];

  const int tid = threadIdx.x;
  const int bx = blockIdx.x % ntiles;
  const int by = blockIdx.x / ntiles;
  const int m0 = by * 128, n0 = bx * 128;
  const int lane = tid & 63;
  const int wv = tid >> 6;
  const int wm = wv >> 1, wn = wv & 1;
  const int r = lane & 15, g = lane >> 4;

  f32x4 acc[4][4] = {};

  for (int kt = 0; kt < 8; ++kt) {
    u32x4 ra[4], rb[4];
#pragma unroll
    for (int i = 0; i < 4; ++i) {
      int ch = tid + i * 256;          // 0..1023
      int row = ch >> 3, c = ch & 7;
      ra[i] = *(const u32x4*)(A + (size_t)(m0 + row) * 512 + kt * 64 + c * 8);
      rb[i] = *(const u32x4*)(Bw + (size_t)(n0 + row) * 512 + kt * 64 + c * 8);
    }
    __syncthreads();  // previous iter's LDS reads done before overwrite
#pragma unroll
    for (int i = 0; i < 4; ++i) {
      int ch = tid + i * 256;
      int row = ch >> 3, c = ch & 7;
      As[row * 8 + (c ^ (row & 7))] = ra[i];
      Bs[row * 8 + (c ^ (row & 7))] = rb[i];
    }
    __syncthreads();
#pragma unroll
    for (int ks = 0; ks < 2; ++ks) {
      short8 a[4], b[4];
#pragma unroll
      for (int mi = 0; mi < 4; ++mi) {
        int row = wm * 64 + mi * 16 + r;
        a[mi] = *(const short8*)&As[row * 8 + ((ks * 4 + g) ^ (row & 7))];
      }
#pragma unroll
      for (int nj = 0; nj < 4; ++nj) {
        int row = wn * 64 + nj * 16 + r;
        b[nj] = *(const short8*)&Bs[row * 8 + ((ks * 4 + g) ^ (row & 7))];
      }
#pragma unroll
      for (int mi = 0; mi < 4; ++mi)
#pragma unroll
        for (int nj = 0; nj < 4; ++nj)
          acc[mi][nj] = __builtin_amdgcn_mfma_f32_16x16x32_bf16(
              a[mi], b[nj], acc[mi][nj], 0, 0, 0);
    }
  }

  // Epilogue. C/D frag layout: col = lane&15, row = (lane>>4)*4 + j  [m89]
  const int ldc = N;
#pragma unroll
  for (int nj = 0; nj < 4; ++nj) {
    int col = n0 + wn * 64 + nj * 16 + r;
    float bcol = bias[col];
#pragma unroll
    for (int mi = 0; mi < 4; ++mi) {
      int rowb = m0 + wm * 64 + mi * 16 + g * 4;
      f32x4 v = acc[mi][nj];
#pragma unroll
      for (int j = 0; j < 4; ++j) {
        float val = v[j] + bcol;
        size_t off = (size_t)(rowb + j) * ldc + col;
        if (OUT_BF16) ((unsigned short*)Cv)[off] = f2bf(val);
        else          ((float*)Cv)[off] = val;
      }
    }
  }
}

// ---------------------------------------------------------------------------
// Sliding-window attention. One wave per (b,s,h); lane = d (D=64 = wave size).
// qkv layout: [m][1536] with q at +0, k at +512, v at +1024 (e = h*64+d).
__global__ __launch_bounds__(256) void swa_kernel(
    const unsigned short* __restrict__ qkv, unsigned short* __restrict__ attn) {
  const int wid = (blockIdx.x * 256 + threadIdx.x) >> 6;  // 0..262143
  const int lane = threadIdx.x & 63;
  const int h = wid & (H_ - 1);
  const int m = wid >> 3;          // b*S + s
  const int s = m & (S_ - 1);

  const unsigned short* qptr = qkv + (size_t)m * 1536 + h * 64 + lane;
  const unsigned short* kptr = qptr + 512;
  const unsigned short* vptr = qptr + 1024;

  const float qf = bf2f(*qptr) * 0.125f;  // 1/sqrt(64)

  float sc[5];
#pragma unroll
  for (int j = 0; j < 5; ++j) {
    int s2 = s + j - 2;
    float p = -1e30f;
    if (s2 >= 0 && s2 < S_) {           // wave-uniform condition
      float kf = bf2f(kptr[(j - 2) * 1536]);
      p = qf * kf;
#pragma unroll
      for (int o = 1; o < 64; o <<= 1) p += __shfl_xor(p, o);
    }
    sc[j] = p;
  }

  float mx = sc[0];
#pragma unroll
  for (int j = 1; j < 5; ++j) mx = fmaxf(mx, sc[j]);
  float e[5], sum = 0.f;
#pragma unroll
  for (int j = 0; j < 5; ++j) { e[j] = __expf(sc[j] - mx); sum += e[j]; }
  float inv = 1.0f / sum;

  float o = 0.f;
#pragma unroll
  for (int j = 0; j < 5; ++j) {
    int s2 = s + j - 2;
    if (s2 >= 0 && s2 < S_) o += e[j] * bf2f(vptr[(j - 2) * 1536]);
  }
  attn[(size_t)m * 512 + h * 64 + lane] = f2bf(o * inv);
}

// ---------------------------------------------------------------------------
extern "C" void kernel_launch(void* const* d_in, const int* in_sizes, int n_in,
                              void* d_out, int out_size, void* d_ws, size_t ws_size,
                              hipStream_t stream) {
  const float* x  = (const float*)d_in[0];
  const float* Wq = (const float*)d_in[1];
  const float* Wk = (const float*)d_in[2];
  const float* Wv = (const float*)d_in[3];
  const float* bq = (const float*)d_in[4];
  const float* bk = (const float*)d_in[5];
  const float* bv = (const float*)d_in[6];
  const float* Wo = (const float*)d_in[7];
  const float* bo = (const float*)d_in[8];
  float* out = (float*)d_out;

  char* ws = (char*)d_ws;
  unsigned short* xb   = (unsigned short*)(ws);               // 33,554,432 B
  unsigned short* qkv  = (unsigned short*)(ws + 33554432);    // 100,663,296 B
  unsigned short* attn = (unsigned short*)(ws + 134217728);   // 33,554,432 B
  unsigned short* Wcat = (unsigned short*)(ws + 167772160);   // 1,572,864 B
  unsigned short* Wob  = (unsigned short*)(ws + 169345024);   // 524,288 B
  float* bcat          = (float*)(ws + 169869312);            // 6,144 B

  cast_x_kernel<<<16384, 256, 0, stream>>>(x, xb);
  cast_w_kernel<<<1024, 256, 0, stream>>>(Wq, Wk, Wv, Wo, bq, bk, bv, Wcat, Wob, bcat);
  // QKV projection: M=32768, N=1536
  gemm_bt<1><<<3072, 256, 0, stream>>>(xb, Wcat, bcat, qkv, 1536, 12);
  // sliding-window attention: 262144 waves
  swa_kernel<<<65536, 256, 0, stream>>>(qkv, attn);
  // output projection: M=32768, N=512, f32 out
  gemm_bt<0><<<1024, 256, 0, stream>>>(attn, Wob, bo, out, 512, 4);
}

// Round 2
// 309.759 us; speedup vs baseline: 1.2108x; 1.2108x over previous
//
#include <hip/hip_runtime.h>

// Problem constants
#define B_ 8
#define S_ 4096
#define E_ 512
#define H_ 8
#define D_ 64
#define M_TOT 32768   // B*S

typedef __attribute__((ext_vector_type(8))) short short8;
typedef __attribute__((ext_vector_type(4))) float f32x4;
typedef __attribute__((ext_vector_type(4))) unsigned int u32x4;

__device__ __forceinline__ float bf2f(unsigned short u) {
  union { unsigned int i; float f; } v; v.i = ((unsigned int)u) << 16; return v.f;
}
__device__ __forceinline__ unsigned short f2bf(float f) {
  union { float f; unsigned int i; } v; v.f = f;
  unsigned int r = v.i + 0x7FFFu + ((v.i >> 16) & 1u);
  return (unsigned short)(r >> 16);
}

// async global->LDS, 16B per lane; LDS dest must be wave-uniform base (+lane*16 by HW)
#define LOAD_LDS16(g, l) __builtin_amdgcn_global_load_lds( \
    (const __attribute__((address_space(1))) void*)(g),     \
    (__attribute__((address_space(3))) void*)(l), 16, 0, 0)

// ---------------------------------------------------------------------------
// Cast x (f32 -> bf16), 4 elems/thread
__global__ __launch_bounds__(256) void cast_x_kernel(
    const float* __restrict__ x, unsigned short* __restrict__ xb) {
  int i = (blockIdx.x * 256 + threadIdx.x) * 4;
  float4 v = *(const float4*)(x + i);
  ushort4 o;
  o.x = f2bf(v.x); o.y = f2bf(v.y); o.z = f2bf(v.z); o.w = f2bf(v.w);
  *(ushort4*)(xb + i) = o;
}

// Cast weights: Wq/Wk/Wv -> Wcat[1536][512] bf16, Wo -> bf16, biases -> bcat
__global__ __launch_bounds__(256) void cast_w_kernel(
    const float* __restrict__ Wq, const float* __restrict__ Wk,
    const float* __restrict__ Wv, const float* __restrict__ Wo,
    const float* __restrict__ bq, const float* __restrict__ bk,
    const float* __restrict__ bv,
    unsigned short* __restrict__ Wcat, unsigned short* __restrict__ Wob,
    float* __restrict__ bcat) {
  int i = blockIdx.x * 256 + threadIdx.x;  // 0..262143
  Wcat[i]          = f2bf(Wq[i]);
  Wcat[262144 + i] = f2bf(Wk[i]);
  Wcat[524288 + i] = f2bf(Wv[i]);
  Wob[i]           = f2bf(Wo[i]);
  if (i < 512) { bcat[i] = bq[i]; bcat[512 + i] = bk[i]; bcat[1024 + i] = bv[i]; }
}

// ---------------------------------------------------------------------------
// C[m][n] = sum_k A[m][k] * Bw[n][k] + bias[n]   (row-major operands, K=512)
// m97 structure: BM=BN=128, BK=64, 4 waves (2x2), global_load_lds width=16,
// LINEAR LDS [128][64] bf16 (gload_lds requires linear dest; beats
// reg-staged+swizzle at this tile per m151).
template<int OUT_BF16>
__global__ __launch_bounds__(256, 2) void gemm_bt(
    const unsigned short* __restrict__ A,   // [M][512] bf16
    const unsigned short* __restrict__ Bw,  // [N][512] bf16
    const float* __restrict__ bias,         // [N] f32
    void* __restrict__ Cv,                  // [M][N] f32 or bf16
    int N, int ntiles) {
  __shared__ unsigned short As[128 * 64];
  __shared__ unsigned short Bs[128 * 64];

  const int tid = threadIdx.x;
  const int bx = blockIdx.x % ntiles;
  const int by = blockIdx.x / ntiles;
  const int m0 = by * 128, n0 = bx * 128;
  const int lane = tid & 63;
  const int wv = tid >> 6;
  const int wm = wv >> 1, wn = wv & 1;
  const int r = lane & 15, g = lane >> 4;

  f32x4 acc[4][4] = {};

  // Staging: 1024 chunks of 16B per tile; wave wv handles chunks
  // [wv*256, wv*256+256) in 4 calls of 64 chunks (one per lane).
  // chunk c -> row = c>>3, col8 = c&7 (row-major [128][64] bf16).
  const int cbase = wv * 256 + lane;

  for (int kt = 0; kt < 8; ++kt) {
    __syncthreads();  // all waves done reading LDS from previous iter
#pragma unroll
    for (int i = 0; i < 4; ++i) {
      int c = cbase + i * 64;
      int row = c >> 3, c8 = c & 7;
      const unsigned short* ga = A + (size_t)(m0 + row) * 512 + kt * 64 + c8 * 8;
      const unsigned short* gb = Bw + (size_t)(n0 + row) * 512 + kt * 64 + c8 * 8;
      char* la = (char*)As + (wv * 256 + i * 64) * 16;  // wave-uniform
      char* lb = (char*)Bs + (wv * 256 + i * 64) * 16;
      LOAD_LDS16(ga, la);
      LOAD_LDS16(gb, lb);
    }
    __syncthreads();  // vmcnt(0) drain + barrier: tile ready
#pragma unroll
    for (int ks = 0; ks < 2; ++ks) {
      short8 a[4], b[4];
#pragma unroll
      for (int mi = 0; mi < 4; ++mi)
        a[mi] = *(const short8*)&As[(wm * 64 + mi * 16 + r) * 64 + ks * 32 + g * 8];
#pragma unroll
      for (int nj = 0; nj < 4; ++nj)
        b[nj] = *(const short8*)&Bs[(wn * 64 + nj * 16 + r) * 64 + ks * 32 + g * 8];
#pragma unroll
      for (int mi = 0; mi < 4; ++mi)
#pragma unroll
        for (int nj = 0; nj < 4; ++nj)
          acc[mi][nj] = __builtin_amdgcn_mfma_f32_16x16x32_bf16(
              a[mi], b[nj], acc[mi][nj], 0, 0, 0);
    }
  }

  // Epilogue. C/D frag layout: col = lane&15, row = (lane>>4)*4 + j  [m89]
  const int ldc = N;
#pragma unroll
  for (int nj = 0; nj < 4; ++nj) {
    int col = n0 + wn * 64 + nj * 16 + r;
    float bcol = bias[col];
#pragma unroll
    for (int mi = 0; mi < 4; ++mi) {
      int rowb = m0 + wm * 64 + mi * 16 + g * 4;
      f32x4 v = acc[mi][nj];
#pragma unroll
      for (int j = 0; j < 4; ++j) {
        float val = v[j] + bcol;
        size_t off = (size_t)(rowb + j) * ldc + col;
        if (OUT_BF16) ((unsigned short*)Cv)[off] = f2bf(val);
        else          ((float*)Cv)[off] = val;
      }
    }
  }
}

// ---------------------------------------------------------------------------
// Sliding-window attention. One THREAD per (m,h): full head-row in registers,
// no cross-lane ops. Two passes: scores (k reads), then output (v reads).
// qkv layout: [m][1536] with q at +0, k at +512, v at +1024 (e = h*64+d).
__global__ __launch_bounds__(256) void swa_kernel(
    const unsigned short* __restrict__ qkv, unsigned short* __restrict__ attn) {
  const int t = blockIdx.x * 256 + threadIdx.x;  // 0..262143
  const int h = t & (H_ - 1);
  const int m = t >> 3;            // b*S + s
  const int s = m & (S_ - 1);

  const unsigned short* base = qkv + (size_t)m * 1536 + h * 64;

  // q row -> f32 registers
  float q[64];
#pragma unroll
  for (int c = 0; c < 8; ++c) {
    short8 v = *(const short8*)(base + c * 8);
#pragma unroll
    for (int j = 0; j < 8; ++j) q[c * 8 + j] = bf2f((unsigned short)v[j]);
  }

  // pass 1: scores
  float sc[5];
#pragma unroll
  for (int w = 0; w < 5; ++w) {
    int s2 = s + w - 2;
    float r = -1e30f;
    if ((unsigned)s2 < (unsigned)S_) {
      const unsigned short* kp = base + (ptrdiff_t)(w - 2) * 1536 + 512;
      float acc = 0.f;
#pragma unroll
      for (int c = 0; c < 8; ++c) {
        short8 v = *(const short8*)(kp + c * 8);
#pragma unroll
        for (int j = 0; j < 8; ++j) acc += q[c * 8 + j] * bf2f((unsigned short)v[j]);
      }
      r = acc * 0.125f;  // 1/sqrt(64)
    }
    sc[w] = r;
  }

  // softmax over 5
  float mx = fmaxf(fmaxf(fmaxf(sc[0], sc[1]), fmaxf(sc[2], sc[3])), sc[4]);
  float e[5], sum = 0.f;
#pragma unroll
  for (int w = 0; w < 5; ++w) { e[w] = __expf(sc[w] - mx); sum += e[w]; }
  float inv = 1.0f / sum;

  // pass 2: output accumulation
  float o[64];
#pragma unroll
  for (int j = 0; j < 64; ++j) o[j] = 0.f;
#pragma unroll
  for (int w = 0; w < 5; ++w) {
    int s2 = s + w - 2;
    if ((unsigned)s2 < (unsigned)S_) {
      float ew = e[w] * inv;
      const unsigned short* vp = base + (ptrdiff_t)(w - 2) * 1536 + 1024;
#pragma unroll
      for (int c = 0; c < 8; ++c) {
        short8 v = *(const short8*)(vp + c * 8);
#pragma unroll
        for (int j = 0; j < 8; ++j) o[c * 8 + j] += ew * bf2f((unsigned short)v[j]);
      }
    }
  }

  unsigned short* op = attn + (size_t)m * 512 + h * 64;
#pragma unroll
  for (int c = 0; c < 8; ++c) {
    short8 ov;
#pragma unroll
    for (int j = 0; j < 8; ++j) ov[j] = (short)f2bf(o[c * 8 + j]);
    *(short8*)(op + c * 8) = ov;
  }
}

// ---------------------------------------------------------------------------
extern "C" void kernel_launch(void* const* d_in, const int* in_sizes, int n_in,
                              void* d_out, int out_size, void* d_ws, size_t ws_size,
                              hipStream_t stream) {
  const float* x  = (const float*)d_in[0];
  const float* Wq = (const float*)d_in[1];
  const float* Wk = (const float*)d_in[2];
  const float* Wv = (const float*)d_in[3];
  const float* bq = (const float*)d_in[4];
  const float* bk = (const float*)d_in[5];
  const float* bv = (const float*)d_in[6];
  const float* Wo = (const float*)d_in[7];
  const float* bo = (const float*)d_in[8];
  float* out = (float*)d_out;

  char* ws = (char*)d_ws;
  unsigned short* xb   = (unsigned short*)(ws);               // 33,554,432 B
  unsigned short* qkv  = (unsigned short*)(ws + 33554432);    // 100,663,296 B
  unsigned short* attn = (unsigned short*)(ws + 134217728);   // 33,554,432 B
  unsigned short* Wcat = (unsigned short*)(ws + 167772160);   // 1,572,864 B
  unsigned short* Wob  = (unsigned short*)(ws + 169345024);   // 524,288 B
  float* bcat          = (float*)(ws + 169869312);            // 6,144 B

  cast_x_kernel<<<16384, 256, 0, stream>>>(x, xb);
  cast_w_kernel<<<1024, 256, 0, stream>>>(Wq, Wk, Wv, Wo, bq, bk, bv, Wcat, Wob, bcat);
  // QKV projection: M=32768, N=1536
  gemm_bt<1><<<3072, 256, 0, stream>>>(xb, Wcat, bcat, qkv, 1536, 12);
  // sliding-window attention: one thread per (m,h)
  swa_kernel<<<1024, 256, 0, stream>>>(qkv, attn);
  // output projection: M=32768, N=512, f32 out
  gemm_bt<0><<<1024, 256, 0, stream>>>(attn, Wob, bo, out, 512, 4);
}